// Round 1
// baseline (74.307 us; speedup 1.0000x reference)
//
#include <hip/hip_runtime.h>
#include <math.h>

#define H      4096
#define NH     32
#define NKV    8
#define HD     128
#define CACHE  2048
#define GROUPS (NH / NKV)
#define SPLITS 8
#define SCALE  0.08838834764831845f   // 1/sqrt(128)

// workspace layout (floats)
#define QOFF 0                         // q_raw[4096]
#define KOFF 4096                      // k_raw[1024]
#define VOFF 5120                      // v_raw[1024]
#define POFF 6144                      // partials: [NH][SPLITS]{m,l,pad,pad,acc[128]}
#define PSTRIDE 132
#define CTXOFF (POFF + NH * SPLITS * PSTRIDE)   // ctx[4096]

// ---------------- QKV GEMV: one wave per output row ----------------
__global__ __launch_bounds__(256) void qkv_gemv(
    const float* __restrict__ x,
    const float* __restrict__ qw, const float* __restrict__ kw,
    const float* __restrict__ vw, float* __restrict__ ws) {
  const int wave = threadIdx.x >> 6;
  const int lane = threadIdx.x & 63;
  const int row  = blockIdx.x * 4 + wave;        // 0..6143

  const float* w;
  float* outp;
  int r;
  if (row < 4096)      { w = qw; r = row;        outp = ws + QOFF; }
  else if (row < 5120) { w = kw; r = row - 4096; outp = ws + KOFF; }
  else                 { w = vw; r = row - 5120; outp = ws + VOFF; }

  const float4* wr = (const float4*)(w + (size_t)r * H);
  const float4* xr = (const float4*)x;
  float sum = 0.f;
#pragma unroll
  for (int j = 0; j < H / 4 / 64; ++j) {         // 16 iters, 16B/lane coalesced
    float4 a = wr[j * 64 + lane];
    float4 b = xr[j * 64 + lane];
    sum += a.x * b.x + a.y * b.y + a.z * b.z + a.w * b.w;
  }
#pragma unroll
  for (int off = 32; off > 0; off >>= 1) sum += __shfl_xor(sum, off);
  if (lane == 0) outp[r] = sum;
}

// ---------------- attention, flash-decode split over positions ----------------
__global__ __launch_bounds__(256) void attn_split(
    const float* __restrict__ kcache, const float* __restrict__ vcache,
    const float* __restrict__ mask,
    const float* __restrict__ cosc, const float* __restrict__ sinc,
    const int* __restrict__ curpos_p, float* __restrict__ ws) {
  const int h     = blockIdx.x;          // q head
  const int split = blockIdx.y;
  const int kh    = h / GROUPS;          // kv head
  const int cur   = curpos_p[0];
  const int total = cur + 1;             // positions 0..cur inclusive (rest masked to -1e9 -> exp==0)
  const int chunk = (total + SPLITS - 1) / SPLITS;
  const int p0    = split * chunk;
  const int p1    = min(p0 + chunk, total);
  const int n     = p1 - p0;

  __shared__ float q_s[HD];
  __shared__ float newk[HD], newv[HD];
  __shared__ float sc[256];              // chunk <= ceil(2048/8)
  __shared__ float red[8];
  __shared__ float accs[HD];

  const int t = threadIdx.x;

  // RoPE on q (this head) and on the new k; new v passthrough
  if (t < HD) {
    const float c  = cosc[(size_t)cur * HD + t];
    const float s  = sinc[(size_t)cur * HD + t];
    const float q1 = ws[QOFF + h * HD + t];
    const float q2 = (t < HD / 2) ? -ws[QOFF + h * HD + t + HD / 2]
                                  :  ws[QOFF + h * HD + t - HD / 2];
    q_s[t] = q1 * c + q2 * s;
    const float k1 = ws[KOFF + kh * HD + t];
    const float k2 = (t < HD / 2) ? -ws[KOFF + kh * HD + t + HD / 2]
                                  :  ws[KOFF + kh * HD + t - HD / 2];
    newk[t] = k1 * c + k2 * s;
    newv[t] = ws[VOFF + kh * HD + t];
  }
  __syncthreads();

  // pass 1: scores — one wave per position, float2 per lane (128 dims / 64 lanes)
  const int wave = t >> 6, lane = t & 63;
  const float2 qv = ((const float2*)q_s)[lane];
  for (int p = p0 + wave; p < p1; p += 4) {
    float2 kv;
    if (p == cur) {
      kv = ((const float2*)newk)[lane];
    } else {
      kv = ((const float2*)(kcache + (size_t)kh * CACHE * HD + (size_t)p * HD))[lane];
    }
    float partial = kv.x * qv.x + kv.y * qv.y;
#pragma unroll
    for (int off = 32; off > 0; off >>= 1) partial += __shfl_xor(partial, off);
    if (lane == 0) sc[p - p0] = partial * SCALE + mask[p];
  }
  __syncthreads();

  // block max
  float m = -INFINITY;
  for (int i = t; i < n; i += 256) m = fmaxf(m, sc[i]);
#pragma unroll
  for (int off = 32; off > 0; off >>= 1) m = fmaxf(m, __shfl_xor(m, off));
  if (lane == 0) red[wave] = m;
  __syncthreads();
  m = fmaxf(fmaxf(red[0], red[1]), fmaxf(red[2], red[3]));

  // exp + sum
  float lsum = 0.f;
  for (int i = t; i < n; i += 256) {
    float e = __expf(sc[i] - m);
    sc[i] = e;
    lsum += e;
  }
#pragma unroll
  for (int off = 32; off > 0; off >>= 1) lsum += __shfl_xor(lsum, off);
  if (lane == 0) red[4 + wave] = lsum;
  __syncthreads();
  const float l = red[4] + red[5] + red[6] + red[7];

  // pass 2: acc[d] = sum_p e[p] * V[p][d]; 2 threads per d (even/odd positions)
  const int d = t & 127;
  const int halfsel = t >> 7;
  float acc = 0.f;
  for (int i = halfsel; i < n; i += 2) {
    const int p = p0 + i;
    const float vv = (p == cur) ? newv[d]
                                : vcache[(size_t)kh * CACHE * HD + (size_t)p * HD + d];
    acc += sc[i] * vv;
  }
  if (halfsel == 1) accs[d] = acc;
  __syncthreads();
  float* part = ws + POFF + (size_t)(h * SPLITS + split) * PSTRIDE;
  if (halfsel == 0) {
    acc += accs[d];
    part[4 + d] = acc;
  }
  if (t == 0) { part[0] = m; part[1] = l; }
}

// ---------------- combine splits ----------------
__global__ __launch_bounds__(128) void attn_combine(float* __restrict__ ws) {
  const int h = blockIdx.x;
  const int d = threadIdx.x;
  __shared__ float ms[SPLITS], ls[SPLITS];
  if (d < SPLITS) {
    const float* part = ws + POFF + (size_t)(h * SPLITS + d) * PSTRIDE;
    ms[d] = part[0];
    ls[d] = part[1];
  }
  __syncthreads();
  float M = -INFINITY;
#pragma unroll
  for (int i = 0; i < SPLITS; ++i) M = fmaxf(M, ms[i]);
  float L = 0.f, w[SPLITS];
#pragma unroll
  for (int i = 0; i < SPLITS; ++i) { w[i] = __expf(ms[i] - M); L += ls[i] * w[i]; }
  float acc = 0.f;
#pragma unroll
  for (int i = 0; i < SPLITS; ++i)
    acc += w[i] * ws[POFF + (size_t)(h * SPLITS + i) * PSTRIDE + 4 + d];
  ws[CTXOFF + h * HD + d] = acc / L;
}

// ---------------- output projection GEMV ----------------
__global__ __launch_bounds__(256) void o_gemv(
    const float* __restrict__ ow, const float* __restrict__ ws,
    float* __restrict__ out) {
  const int wave = threadIdx.x >> 6;
  const int lane = threadIdx.x & 63;
  const int row  = blockIdx.x * 4 + wave;
  const float4* wr = (const float4*)(ow + (size_t)row * H);
  const float4* xr = (const float4*)(ws + CTXOFF);
  float sum = 0.f;
#pragma unroll
  for (int j = 0; j < H / 4 / 64; ++j) {
    float4 a = wr[j * 64 + lane];
    float4 b = xr[j * 64 + lane];
    sum += a.x * b.x + a.y * b.y + a.z * b.z + a.w * b.w;
  }
#pragma unroll
  for (int off = 32; off > 0; off >>= 1) sum += __shfl_xor(sum, off);
  if (lane == 0) out[row] = sum;
}

extern "C" void kernel_launch(void* const* d_in, const int* in_sizes, int n_in,
                              void* d_out, int out_size, void* d_ws, size_t ws_size,
                              hipStream_t stream) {
  const float* hs   = (const float*)d_in[0];   // hidden_states (1,1,4096)
  const float* mask = (const float*)d_in[1];   // (1,1,1,2048)
  const float* kc   = (const float*)d_in[2];   // (1,8,2048,128)
  const float* vc   = (const float*)d_in[3];
  const float* qw   = (const float*)d_in[4];   // (4096,4096)
  const float* kw   = (const float*)d_in[5];   // (1024,4096)
  const float* vw   = (const float*)d_in[6];   // (1024,4096)
  const float* ow   = (const float*)d_in[7];   // (4096,4096)
  const float* cosc = (const float*)d_in[8];   // (1,4096,128)
  const float* sinc = (const float*)d_in[9];
  const int*   cur  = (const int*)d_in[11];    // current_pos scalar
  float* ws  = (float*)d_ws;
  float* out = (float*)d_out;

  qkv_gemv<<<1536, 256, 0, stream>>>(hs, qw, kw, vw, ws);
  attn_split<<<dim3(NH, SPLITS), 256, 0, stream>>>(kc, vc, mask, cosc, sinc, cur, ws);
  attn_combine<<<NH, 128, 0, stream>>>(ws);
  o_gemv<<<1024, 256, 0, stream>>>(ow, ws, out);
}

// Round 2
// 42.653 us; speedup vs baseline: 1.7421x; 1.7421x over previous
//
#include <hip/hip_runtime.h>
#include <math.h>

#define H      4096
#define NH     32
#define NKV    8
#define HD     128
#define CACHE  2048
#define GROUPS (NH / NKV)
#define CHUNK  32                      // positions per attention block
#define NSPL   (CACHE / CHUNK)         // max splits = 64
#define KSTR   132                     // LDS row stride (floats), 16B-aligned, 4-way max conflict
#define SCALE  0.08838834764831845f    // 1/sqrt(128)

// workspace layout (floats)
#define QOFF 0                         // q_raw[4096]
#define KOFF 4096                      // k_raw[1024]
#define VOFF 5120                      // v_raw[1024]
#define POFF 6144                      // partials: [NH][NSPL]{m,l,pad,pad,acc[128]}
#define PSTRIDE 132
#define CTXOFF (POFF + NH * NSPL * PSTRIDE)   // ctx[4096]

// ---------------- QKV GEMV: one wave per output row ----------------
__global__ __launch_bounds__(256) void qkv_gemv(
    const float* __restrict__ x,
    const float* __restrict__ qw, const float* __restrict__ kw,
    const float* __restrict__ vw, float* __restrict__ ws) {
  const int wave = threadIdx.x >> 6;
  const int lane = threadIdx.x & 63;
  const int row  = blockIdx.x * 4 + wave;        // 0..6143

  const float* w;
  float* outp;
  int r;
  if (row < 4096)      { w = qw; r = row;        outp = ws + QOFF; }
  else if (row < 5120) { w = kw; r = row - 4096; outp = ws + KOFF; }
  else                 { w = vw; r = row - 5120; outp = ws + VOFF; }

  const float4* wr = (const float4*)(w + (size_t)r * H);
  const float4* xr = (const float4*)x;
  float sum = 0.f;
#pragma unroll
  for (int j = 0; j < H / 4 / 64; ++j) {         // 16 iters, 16B/lane coalesced
    float4 a = wr[j * 64 + lane];
    float4 b = xr[j * 64 + lane];
    sum += a.x * b.x + a.y * b.y + a.z * b.z + a.w * b.w;
  }
#pragma unroll
  for (int off = 32; off > 0; off >>= 1) sum += __shfl_xor(sum, off);
  if (lane == 0) outp[r] = sum;
}

// ------------- attention: block = (kv head, 32-pos chunk), all 4 q-heads -------------
__global__ __launch_bounds__(256) void attn_split(
    const float* __restrict__ kcache, const float* __restrict__ vcache,
    const float* __restrict__ cosc, const float* __restrict__ sinc,
    const int* __restrict__ curp, float* __restrict__ ws) {
  const int kh    = blockIdx.x;
  const int split = blockIdx.y;
  const int cur   = curp[0];
  const int total = cur + 1;
  const int p0    = split * CHUNK;
  if (p0 >= total) return;

  __shared__ float Ks[CHUNK * KSTR];
  __shared__ float Vs[CHUNK * KSTR];
  __shared__ float q_s[GROUPS * HD];
  __shared__ float es[GROUPS][CHUNK];

  const int t = threadIdx.x;

  // ---- stage K/V chunk into LDS: batched float4 loads, 8 rows/round
  {
    const int r4 = t >> 5;            // 0..7
    const int c4 = (t & 31) * 4;      // float offset within row
    const float* kb = kcache + (size_t)kh * CACHE * HD;
    const float* vb = vcache + (size_t)kh * CACHE * HD;
#pragma unroll
    for (int rr = 0; rr < CHUNK; rr += 8) {
      const int row = rr + r4;
      const int p   = min(p0 + row, cur);      // clamp: rows past cur hold garbage, masked later
      if (p0 + row != cur) {                   // row 'cur' filled from fresh k/v below
        float4 kv = *(const float4*)(kb + (size_t)p * HD + c4);
        float4 vv = *(const float4*)(vb + (size_t)p * HD + c4);
        *(float4*)&Ks[row * KSTR + c4] = kv;
        *(float4*)&Vs[row * KSTR + c4] = vv;
      }
    }
  }
  // ---- RoPE q for this group's 4 heads (512 values, 2/thread)
#pragma unroll
  for (int i = 0; i < 2; ++i) {
    const int idx = t + i * 256;
    const int qh = idx >> 7, d = idx & 127;
    const int h = kh * GROUPS + qh;
    const float c  = cosc[(size_t)cur * HD + d];
    const float s  = sinc[(size_t)cur * HD + d];
    const float x1 = ws[QOFF + h * HD + d];
    const float x2 = (d < HD / 2) ? -ws[QOFF + h * HD + d + HD / 2]
                                  :  ws[QOFF + h * HD + d - HD / 2];
    q_s[qh * HD + d] = x1 * c + x2 * s;
  }
  // ---- fresh k (RoPE'd) / v into row cur-p0 if this chunk contains cur
  if (cur >= p0 && cur < p0 + CHUNK) {
    const int row = cur - p0;
    if (t < HD) {
      const int d = t;
      const float c  = cosc[(size_t)cur * HD + d];
      const float s  = sinc[(size_t)cur * HD + d];
      const float k1 = ws[KOFF + kh * HD + d];
      const float k2 = (d < HD / 2) ? -ws[KOFF + kh * HD + d + HD / 2]
                                    :  ws[KOFF + kh * HD + d - HD / 2];
      Ks[row * KSTR + d] = k1 * c + k2 * s;
    } else if (t < 2 * HD) {
      const int d = t - HD;
      Vs[row * KSTR + d] = ws[VOFF + kh * HD + d];
    }
  }
  __syncthreads();

  // ---- scores + softmax: thread t<128 owns one (qh, pos); 32-lane group = one qh
  if (t < 128) {
    const int qh = t >> 5, pos = t & 31;
    float4 a = make_float4(0.f, 0.f, 0.f, 0.f);
#pragma unroll
    for (int j = 0; j < HD / 4; ++j) {
      float4 kv = *(const float4*)&Ks[pos * KSTR + j * 4];
      float4 qv = *(const float4*)&q_s[qh * HD + j * 4];
      a.x += kv.x * qv.x; a.y += kv.y * qv.y;
      a.z += kv.z * qv.z; a.w += kv.w * qv.w;
    }
    float s = (a.x + a.y + a.z + a.w) * SCALE;
    const bool valid = (p0 + pos) < total;
    s = valid ? s : -INFINITY;
    float m = s;
#pragma unroll
    for (int off = 16; off > 0; off >>= 1) m = fmaxf(m, __shfl_xor(m, off));
    const float e = valid ? __expf(s - m) : 0.f;
    float l = e;
#pragma unroll
    for (int off = 16; off > 0; off >>= 1) l += __shfl_xor(l, off);
    es[qh][pos] = e;
    if (pos == 0) {
      float* part = ws + POFF + (size_t)((kh * GROUPS + qh) * NSPL + split) * PSTRIDE;
      part[0] = m; part[1] = l;
    }
  }
  __syncthreads();

  // ---- P.V from LDS: thread -> (qh, d-pair), unrolled 32-pos loop
  {
    const int qh = t >> 6;
    const int d0 = (t & 63) * 2;
    float2 acc = make_float2(0.f, 0.f);
#pragma unroll
    for (int pos = 0; pos < CHUNK; ++pos) {
      const float w = es[qh][pos];
      const float2 vv = *(const float2*)&Vs[pos * KSTR + d0];
      acc.x += w * vv.x; acc.y += w * vv.y;
    }
    float* part = ws + POFF + (size_t)((kh * GROUPS + qh) * NSPL + split) * PSTRIDE;
    part[4 + d0]     = acc.x;
    part[4 + d0 + 1] = acc.y;
  }
}

// ---------------- combine splits ----------------
__global__ __launch_bounds__(128) void attn_combine(
    const int* __restrict__ curp, float* __restrict__ ws) {
  const int h = blockIdx.x;
  const int t = threadIdx.x;
  const int total = curp[0] + 1;
  const int nspl = (total + CHUNK - 1) / CHUNK;
  __shared__ float wsh[64];
  __shared__ float Lsh;

  if (t < 64) {
    float mt = -INFINITY, lt = 0.f;
    if (t < nspl) {
      const float* part = ws + POFF + (size_t)(h * NSPL + t) * PSTRIDE;
      mt = part[0]; lt = part[1];
    }
    float M = mt;
#pragma unroll
    for (int off = 32; off > 0; off >>= 1) M = fmaxf(M, __shfl_xor(M, off));
    const float w = (t < nspl) ? __expf(mt - M) : 0.f;
    float lw = lt * w;
#pragma unroll
    for (int off = 32; off > 0; off >>= 1) lw += __shfl_xor(lw, off);
    wsh[t] = w;
    if (t == 0) Lsh = lw;
  }
  __syncthreads();

  const float Linv = 1.f / Lsh;
  float acc = 0.f;
#pragma unroll 8
  for (int i = 0; i < nspl; ++i)
    acc += wsh[i] * ws[POFF + (size_t)(h * NSPL + i) * PSTRIDE + 4 + t];
  ws[CTXOFF + h * HD + t] = acc * Linv;
}

// ---------------- output projection GEMV ----------------
__global__ __launch_bounds__(256) void o_gemv(
    const float* __restrict__ ow, const float* __restrict__ ws,
    float* __restrict__ out) {
  const int wave = threadIdx.x >> 6;
  const int lane = threadIdx.x & 63;
  const int row  = blockIdx.x * 4 + wave;
  const float4* wr = (const float4*)(ow + (size_t)row * H);
  const float4* xr = (const float4*)(ws + CTXOFF);
  float sum = 0.f;
#pragma unroll
  for (int j = 0; j < H / 4 / 64; ++j) {
    float4 a = wr[j * 64 + lane];
    float4 b = xr[j * 64 + lane];
    sum += a.x * b.x + a.y * b.y + a.z * b.z + a.w * b.w;
  }
#pragma unroll
  for (int off = 32; off > 0; off >>= 1) sum += __shfl_xor(sum, off);
  if (lane == 0) out[row] = sum;
}

extern "C" void kernel_launch(void* const* d_in, const int* in_sizes, int n_in,
                              void* d_out, int out_size, void* d_ws, size_t ws_size,
                              hipStream_t stream) {
  const float* hs   = (const float*)d_in[0];   // hidden_states (1,1,4096)
  const float* kc   = (const float*)d_in[2];   // (1,8,2048,128)
  const float* vc   = (const float*)d_in[3];
  const float* qw   = (const float*)d_in[4];   // (4096,4096)
  const float* kw   = (const float*)d_in[5];   // (1024,4096)
  const float* vw   = (const float*)d_in[6];   // (1024,4096)
  const float* ow   = (const float*)d_in[7];   // (4096,4096)
  const float* cosc = (const float*)d_in[8];   // (1,4096,128)
  const float* sinc = (const float*)d_in[9];
  const int*   cur  = (const int*)d_in[11];    // current_pos scalar
  float* ws  = (float*)d_ws;
  float* out = (float*)d_out;

  qkv_gemv<<<1536, 256, 0, stream>>>(hs, qw, kw, vw, ws);
  attn_split<<<dim3(NKV, NSPL), 256, 0, stream>>>(kc, vc, cosc, sinc, cur, ws);
  attn_combine<<<NH, 128, 0, stream>>>(cur, ws);
  o_gemv<<<1024, 256, 0, stream>>>(ow, ws, out);
}

// Round 3
// 41.913 us; speedup vs baseline: 1.7729x; 1.0176x over previous
//
#include <hip/hip_runtime.h>
#include <math.h>

#define H      4096
#define NH     32
#define NKV    8
#define HD     128
#define CACHE  2048
#define GROUPS (NH / NKV)
#define CHUNK  32                      // positions per attention block
#define NSPL   (CACHE / CHUNK)         // max splits = 64
#define KSTR   132                     // LDS row stride (floats)
#define SCALE  0.08838834764831845f    // 1/sqrt(128)

// workspace layout (floats)
#define QOFF 0                         // q_raw[4096]
#define KOFF 4096                      // k_raw[1024]
#define VOFF 5120                      // v_raw[1024]
#define POFF 6144                      // partials: [NH][NSPL]{m,l,pad,pad,acc[128]}
#define PSTRIDE 132
#define CTXOFF (POFF + NH * NSPL * PSTRIDE)   // ctx[4096]

// ---------------- QKV GEMV: wave per row, 16-deep load pipeline ----------------
__global__ __launch_bounds__(256) void qkv_gemv(
    const float* __restrict__ x,
    const float* __restrict__ qw, const float* __restrict__ kw,
    const float* __restrict__ vw, float* __restrict__ ws) {
  __shared__ float xs[H];              // 16 KB
  const int t = threadIdx.x;
  {
    const float4* xr = (const float4*)x;
    float4* xsv = (float4*)xs;
#pragma unroll
    for (int i = 0; i < 4; ++i) xsv[i * 256 + t] = xr[i * 256 + t];
  }
  __syncthreads();

  const int wave = t >> 6;
  const int lane = t & 63;
  const int row  = blockIdx.x * 4 + wave;        // 0..6143

  const float* w;
  float* outp;
  int r;
  if (row < 4096)      { w = qw; r = row;        outp = ws + QOFF; }
  else if (row < 5120) { w = kw; r = row - 4096; outp = ws + KOFF; }
  else                 { w = vw; r = row - 5120; outp = ws + VOFF; }

  const float4* wr = (const float4*)(w + (size_t)r * H);
  float4 a[16];
#pragma unroll
  for (int j = 0; j < 16; ++j) a[j] = wr[j * 64 + lane];   // 16 loads in flight

  float sum = 0.f;
#pragma unroll
  for (int j = 0; j < 16; ++j) {
    const float4 b = *(const float4*)&xs[(j * 64 + lane) * 4];
    sum = fmaf(a[j].x, b.x, sum);
    sum = fmaf(a[j].y, b.y, sum);
    sum = fmaf(a[j].z, b.z, sum);
    sum = fmaf(a[j].w, b.w, sum);
  }
#pragma unroll
  for (int off = 32; off > 0; off >>= 1) sum += __shfl_xor(sum, off);
  if (lane == 0) outp[r] = sum;
}

// ------------- attention: block = (kv head, 32-pos chunk), all 4 q-heads -------------
__global__ __launch_bounds__(256) void attn_split(
    const float* __restrict__ kcache, const float* __restrict__ vcache,
    const float* __restrict__ cosc, const float* __restrict__ sinc,
    const int* __restrict__ curp, float* __restrict__ ws) {
  const int kh    = blockIdx.x;
  const int split = blockIdx.y;
  const int cur   = curp[0];
  const int total = cur + 1;
  const int p0    = split * CHUNK;
  if (p0 >= total) return;

  __shared__ float Ks[CHUNK * KSTR];
  __shared__ float Vs[CHUNK * KSTR];
  __shared__ float q_s[GROUPS * HD];
  __shared__ float es[GROUPS][CHUNK];

  const int t = threadIdx.x;

  // ---- stage K/V chunk into LDS: batched float4 loads, 8 rows/round
  {
    const int r4 = t >> 5;            // 0..7
    const int c4 = (t & 31) * 4;      // float offset within row
    const float* kb = kcache + (size_t)kh * CACHE * HD;
    const float* vb = vcache + (size_t)kh * CACHE * HD;
#pragma unroll
    for (int rr = 0; rr < CHUNK; rr += 8) {
      const int row = rr + r4;
      const int p   = min(p0 + row, cur);      // clamp: rows past cur masked later
      if (p0 + row != cur) {                   // row 'cur' filled from fresh k/v below
        float4 kv = *(const float4*)(kb + (size_t)p * HD + c4);
        float4 vv = *(const float4*)(vb + (size_t)p * HD + c4);
        *(float4*)&Ks[row * KSTR + c4] = kv;
        *(float4*)&Vs[row * KSTR + c4] = vv;
      }
    }
  }
  // ---- RoPE q for this group's 4 heads (512 values, 2/thread)
#pragma unroll
  for (int i = 0; i < 2; ++i) {
    const int idx = t + i * 256;
    const int qh = idx >> 7, d = idx & 127;
    const int h = kh * GROUPS + qh;
    const float c  = cosc[(size_t)cur * HD + d];
    const float s  = sinc[(size_t)cur * HD + d];
    const float x1 = ws[QOFF + h * HD + d];
    const float x2 = (d < HD / 2) ? -ws[QOFF + h * HD + d + HD / 2]
                                  :  ws[QOFF + h * HD + d - HD / 2];
    q_s[qh * HD + d] = x1 * c + x2 * s;
  }
  // ---- fresh k (RoPE'd) / v into row cur-p0 if this chunk contains cur
  if (cur >= p0 && cur < p0 + CHUNK) {
    const int row = cur - p0;
    if (t < HD) {
      const int d = t;
      const float c  = cosc[(size_t)cur * HD + d];
      const float s  = sinc[(size_t)cur * HD + d];
      const float k1 = ws[KOFF + kh * HD + d];
      const float k2 = (d < HD / 2) ? -ws[KOFF + kh * HD + d + HD / 2]
                                    :  ws[KOFF + kh * HD + d - HD / 2];
      Ks[row * KSTR + d] = k1 * c + k2 * s;
    } else if (t < 2 * HD) {
      const int d = t - HD;
      Vs[row * KSTR + d] = ws[VOFF + kh * HD + d];
    }
  }
  __syncthreads();

  // ---- scores + softmax: thread t<128 owns one (qh, pos); 32-lane group = one qh
  if (t < 128) {
    const int qh = t >> 5, pos = t & 31;
    float4 a = make_float4(0.f, 0.f, 0.f, 0.f);
#pragma unroll
    for (int j = 0; j < HD / 4; ++j) {
      float4 kv = *(const float4*)&Ks[pos * KSTR + j * 4];
      float4 qv = *(const float4*)&q_s[qh * HD + j * 4];
      a.x += kv.x * qv.x; a.y += kv.y * qv.y;
      a.z += kv.z * qv.z; a.w += kv.w * qv.w;
    }
    float s = (a.x + a.y + a.z + a.w) * SCALE;
    const bool valid = (p0 + pos) < total;
    s = valid ? s : -INFINITY;
    float m = s;
#pragma unroll
    for (int off = 16; off > 0; off >>= 1) m = fmaxf(m, __shfl_xor(m, off));
    const float e = valid ? __expf(s - m) : 0.f;
    float l = e;
#pragma unroll
    for (int off = 16; off > 0; off >>= 1) l += __shfl_xor(l, off);
    es[qh][pos] = e;
    if (pos == 0) {
      float* part = ws + POFF + (size_t)((kh * GROUPS + qh) * NSPL + split) * PSTRIDE;
      part[0] = m; part[1] = l;
    }
  }
  __syncthreads();

  // ---- P.V from LDS: thread -> (qh, d-pair), unrolled 32-pos loop
  {
    const int qh = t >> 6;
    const int d0 = (t & 63) * 2;
    float2 acc = make_float2(0.f, 0.f);
#pragma unroll
    for (int pos = 0; pos < CHUNK; ++pos) {
      const float w = es[qh][pos];
      const float2 vv = *(const float2*)&Vs[pos * KSTR + d0];
      acc.x += w * vv.x; acc.y += w * vv.y;
    }
    float* part = ws + POFF + (size_t)((kh * GROUPS + qh) * NSPL + split) * PSTRIDE;
    part[4 + d0]     = acc.x;
    part[4 + d0 + 1] = acc.y;
  }
}

// ---------------- combine splits ----------------
__global__ __launch_bounds__(128) void attn_combine(
    const int* __restrict__ curp, float* __restrict__ ws) {
  const int h = blockIdx.x;
  const int t = threadIdx.x;
  const int total = curp[0] + 1;
  const int nspl = (total + CHUNK - 1) / CHUNK;
  __shared__ float wsh[64];
  __shared__ float Lsh;

  if (t < 64) {
    float mt = -INFINITY, lt = 0.f;
    if (t < nspl) {
      const float* part = ws + POFF + (size_t)(h * NSPL + t) * PSTRIDE;
      mt = part[0]; lt = part[1];
    }
    float M = mt;
#pragma unroll
    for (int off = 32; off > 0; off >>= 1) M = fmaxf(M, __shfl_xor(M, off));
    const float w = (t < nspl) ? __expf(mt - M) : 0.f;
    float lw = lt * w;
#pragma unroll
    for (int off = 32; off > 0; off >>= 1) lw += __shfl_xor(lw, off);
    wsh[t] = w;
    if (t == 0) Lsh = lw;
  }
  __syncthreads();

  const float Linv = 1.f / Lsh;
  float acc = 0.f;
#pragma unroll 8
  for (int i = 0; i < nspl; ++i)
    acc += wsh[i] * ws[POFF + (size_t)(h * NSPL + i) * PSTRIDE + 4 + t];
  ws[CTXOFF + h * HD + t] = acc * Linv;
}

// ---------------- output projection GEMV: same 16-deep pipeline ----------------
__global__ __launch_bounds__(256) void o_gemv(
    const float* __restrict__ ow, const float* __restrict__ ws,
    float* __restrict__ out) {
  __shared__ float xs[H];              // 16 KB (ctx)
  const int t = threadIdx.x;
  {
    const float4* xr = (const float4*)(ws + CTXOFF);
    float4* xsv = (float4*)xs;
#pragma unroll
    for (int i = 0; i < 4; ++i) xsv[i * 256 + t] = xr[i * 256 + t];
  }
  __syncthreads();

  const int wave = t >> 6;
  const int lane = t & 63;
  const int row  = blockIdx.x * 4 + wave;

  const float4* wr = (const float4*)(ow + (size_t)row * H);
  float4 a[16];
#pragma unroll
  for (int j = 0; j < 16; ++j) a[j] = wr[j * 64 + lane];

  float sum = 0.f;
#pragma unroll
  for (int j = 0; j < 16; ++j) {
    const float4 b = *(const float4*)&xs[(j * 64 + lane) * 4];
    sum = fmaf(a[j].x, b.x, sum);
    sum = fmaf(a[j].y, b.y, sum);
    sum = fmaf(a[j].z, b.z, sum);
    sum = fmaf(a[j].w, b.w, sum);
  }
#pragma unroll
  for (int off = 32; off > 0; off >>= 1) sum += __shfl_xor(sum, off);
  if (lane == 0) out[row] = sum;
}

extern "C" void kernel_launch(void* const* d_in, const int* in_sizes, int n_in,
                              void* d_out, int out_size, void* d_ws, size_t ws_size,
                              hipStream_t stream) {
  const float* hs   = (const float*)d_in[0];   // hidden_states (1,1,4096)
  const float* kc   = (const float*)d_in[2];   // (1,8,2048,128)
  const float* vc   = (const float*)d_in[3];
  const float* qw   = (const float*)d_in[4];   // (4096,4096)
  const float* kw   = (const float*)d_in[5];   // (1024,4096)
  const float* vw   = (const float*)d_in[6];   // (1024,4096)
  const float* ow   = (const float*)d_in[7];   // (4096,4096)
  const float* cosc = (const float*)d_in[8];   // (1,4096,128)
  const float* sinc = (const float*)d_in[9];
  const int*   cur  = (const int*)d_in[11];    // current_pos scalar
  float* ws  = (float*)d_ws;
  float* out = (float*)d_out;

  qkv_gemv<<<1536, 256, 0, stream>>>(hs, qw, kw, vw, ws);
  attn_split<<<dim3(NKV, NSPL), 256, 0, stream>>>(kc, vc, cosc, sinc, cur, ws);
  attn_combine<<<NH, 128, 0, stream>>>(cur, ws);
  o_gemv<<<1024, 256, 0, stream>>>(ow, ws, out);
}